// Round 3
// baseline (342.635 us; speedup 1.0000x reference)
//
#include <hip/hip_runtime.h>
#include <math.h>

#define BB 8
#define TT 4096
#define TP1 4097
#define HH 1024
#define NHD 16

__device__ __forceinline__ float dot4(const float4& a, const float4& b) {
  return a.x*b.x + a.y*b.y + a.z*b.z + a.w*b.w;
}

// ---------------- K1: qbuf[b][j] = 0.125*(cell[b,:]·Wq[j,:] + bq[j]) ----------------
__global__ __launch_bounds__(256) void k_q(const float* __restrict__ cell,
                                           const float* __restrict__ Wq,
                                           const float* __restrict__ bq,
                                           float* __restrict__ qbuf) {
  __shared__ float cs[BB * HH];  // 32 KB
  int tid = threadIdx.x;
  #pragma unroll
  for (int m = 0; m < 8; m++) {
    int idx4 = tid + (m << 8);
    ((float4*)cs)[idx4] = ((const float4*)cell)[idx4];
  }
  __syncthreads();
  int jj = tid >> 6, lane = tid & 63;
  int j = blockIdx.x * 4 + jj;
  float acc[BB];
  #pragma unroll
  for (int b = 0; b < BB; b++) acc[b] = 0.f;
  #pragma unroll
  for (int k = 0; k < 4; k++) {
    int i = (k << 8) + (lane << 2);
    float4 w = *(const float4*)&Wq[(size_t)j * HH + i];
    #pragma unroll
    for (int b = 0; b < BB; b++) acc[b] += dot4(w, *(const float4*)&cs[b * HH + i]);
  }
  #pragma unroll
  for (int b = 0; b < BB; b++) {
    acc[b] += __shfl_xor(acc[b], 1);  acc[b] += __shfl_xor(acc[b], 2);
    acc[b] += __shfl_xor(acc[b], 4);  acc[b] += __shfl_xor(acc[b], 8);
    acc[b] += __shfl_xor(acc[b], 16); acc[b] += __shfl_xor(acc[b], 32);
  }
  if (lane == 0) {
    float bqv = bq[j];
    #pragma unroll
    for (int b = 0; b < BB; b++) qbuf[b * HH + j] = 0.125f * (acc[b] + bqv);
  }
}

// ---------------- K2: qWkT[b][i][h] = sum_d qbuf[b][h*64+d]*Wk[h*64+d][i]; qbk[b][h] ----------------
__global__ __launch_bounds__(256) void k_qwk(const float* __restrict__ qbuf,
                                             const float* __restrict__ Wk,
                                             const float* __restrict__ bk,
                                             float* __restrict__ qWkT,
                                             float* __restrict__ qbk) {
  __shared__ float q_s[BB * 64];
  __shared__ float red[4 * 64 * 9];  // padded +1
  int tid = threadIdx.x;
  int h = blockIdx.x >> 4, ic = blockIdx.x & 15;
  if (tid < 128) {
    int b = tid >> 4, dq = tid & 15;
    ((float4*)q_s)[tid] = ((const float4*)qbuf)[(b << 8) + (h << 4) + dq];
  }
  __syncthreads();
  int dg = tid >> 6, lane = tid & 63;
  int i = (ic << 6) + lane;
  float acc[BB];
  #pragma unroll
  for (int b = 0; b < BB; b++) acc[b] = 0.f;
  #pragma unroll
  for (int dd = 0; dd < 16; dd++) {
    int d = (dg << 4) + dd;
    float wk = Wk[(size_t)((h << 6) + d) * HH + i];
    #pragma unroll
    for (int b = 0; b < BB; b++) acc[b] += q_s[(b << 6) + d] * wk;
  }
  #pragma unroll
  for (int b = 0; b < BB; b++) red[((dg << 6) + lane) * 9 + b] = acc[b];
  __syncthreads();
  #pragma unroll
  for (int r = 0; r < 2; r++) {
    int o = tid + (r << 8);           // 512 outputs = 64 i x 8 b
    int il = o >> 3, b = o & 7;
    float s = 0.f;
    #pragma unroll
    for (int g = 0; g < 4; g++) s += red[((g << 6) + il) * 9 + b];
    qWkT[((size_t)(b << 10) + (ic << 6) + il) * NHD + h] = s;
  }
  if (ic == 0 && tid < 8) {
    float s = 0.f;
    for (int d = 0; d < 64; d++) s += q_s[(tid << 6) + d] * bk[(h << 6) + d];
    qbk[tid * NHD + h] = s;
  }
}

// ---------------- K3 (FUSED v3): scores -> exp -> PV, two LDS-chunk passes ----------------
// grid 512 = b(8) x g(64); block 512 thr (8 waves). 64 rows/block.
// LDS: KV[64][260] (one 256-i chunk, stride/4 === 1 mod 8 -> saturated banking) = 65 KB
//      + E[64][20] = 5 KB  ->  70 KB -> 2 blocks/CU (4 waves/SIMD).
// Scores pass: lane = row r; wave w owns i-slice [c*256+32w, +32). Per 4-i step:
//   1 ds_read_b128 (kv) + 16 wave-uniform float4 q-loads (scalarize to s_load)
//   + 64 FMAs into acc[16] (persists across chunks). No LDS for q at all.
// Reduce: red overlay [8][64][17] in KV (17-stride -> conflict-free), e-phase wave w
//   handles h=w,w+8 for all 64 rows; Spart via shfl; E written [64][20] (b128-aligned).
// PV pass: re-stage the same chunks (hid is L3-resident, pass 2 ~free on HBM);
//   waves 0-3 active: wave=hq, lane=i-quad; per row: 1 kv b128 + 1 uniform e b128
//   -> 16 FMAs; acc 16 VGPR; per-chunk coalesced ctxp writes. No atomics, no spill:
//   staging regs 8xfloat4, peak ~75 VGPR under launch_bounds(512,4).
__global__ __launch_bounds__(512, 4) void k_sctx(const float* __restrict__ hid,
                                                 const float* __restrict__ qWkT,
                                                 const float* __restrict__ qbk,
                                                 const int* __restrict__ mask,
                                                 float* __restrict__ ctxp,
                                                 float* __restrict__ Spart) {
  __shared__ float KV[16640];   // [64][260]; red overlay [8][64][17] (8704 floats)
  __shared__ float E[1280];     // [64][20]
  int tid = threadIdx.x;
  int b = blockIdx.x >> 6, g = blockIdx.x & 63;
  int t0 = g << 6;
  int w = __builtin_amdgcn_readfirstlane(tid >> 6);
  int lane = tid & 63;
  const float* src = hid + ((size_t)b * TP1 + t0) * HH;

  // staging mapping: thread -> (row sr, i-quad base si8); 8 float4 per chunk
  int sr = tid >> 3, si8 = tid & 7;
  const float* gs = src + (size_t)sr * HH + (si8 << 2);
  float* kvw = KV + sr * 260 + (si8 << 2);

  float4 stg[8];
  #pragma unroll
  for (int m = 0; m < 8; m++) stg[m] = *(const float4*)(gs + (m << 5));
  #pragma unroll
  for (int m = 0; m < 8; m++) *(float4*)(kvw + (m << 5)) = stg[m];
  __syncthreads();

  // ---------------- scores pass ----------------
  float acc[16];
  #pragma unroll
  for (int h = 0; h < 16; h++) acc[h] = 0.f;
  const float* qb = qWkT + ((size_t)b << 14);
  const float* kvr = KV + lane * 260 + (w << 5);

  for (int c = 0; c < 4; c++) {
    if (c < 3) {  // issue next chunk early (T14)
      const float* gs2 = gs + ((c + 1) << 8);
      #pragma unroll
      for (int m = 0; m < 8; m++) stg[m] = *(const float4*)(gs2 + (m << 5));
    }
    int i0 = (c << 8) + (w << 5);
    #pragma unroll
    for (int s = 0; s < 8; s++) {
      float4 kvq = *(const float4*)(kvr + (s << 2));
      const float* qp = qb + ((size_t)(i0 + (s << 2)) << 4);
      #pragma unroll
      for (int ii = 0; ii < 4; ii++) {
        float kvv = (ii == 0) ? kvq.x : (ii == 1) ? kvq.y : (ii == 2) ? kvq.z : kvq.w;
        const float* qi = qp + (ii << 4);
        float4 q0 = *(const float4*)(qi);
        float4 q1 = *(const float4*)(qi + 4);
        float4 q2 = *(const float4*)(qi + 8);
        float4 q3 = *(const float4*)(qi + 12);
        acc[0]  += kvv * q0.x;  acc[1]  += kvv * q0.y;
        acc[2]  += kvv * q0.z;  acc[3]  += kvv * q0.w;
        acc[4]  += kvv * q1.x;  acc[5]  += kvv * q1.y;
        acc[6]  += kvv * q1.z;  acc[7]  += kvv * q1.w;
        acc[8]  += kvv * q2.x;  acc[9]  += kvv * q2.y;
        acc[10] += kvv * q2.z;  acc[11] += kvv * q2.w;
        acc[12] += kvv * q3.x;  acc[13] += kvv * q3.y;
        acc[14] += kvv * q3.z;  acc[15] += kvv * q3.w;
      }
    }
    __syncthreads();
    if (c < 3) {
      #pragma unroll
      for (int m = 0; m < 8; m++) *(float4*)(kvw + (m << 5)) = stg[m];
    }
    __syncthreads();
  }

  // issue PV chunk-0 loads now; they complete under the red/e phases
  #pragma unroll
  for (int m = 0; m < 8; m++) stg[m] = *(const float4*)(gs + (m << 5));

  // red overlay: red[w][r][h] at KV[w*1088 + r*17 + h] (17-stride: conflict-free)
  {
    float* rp = KV + w * 1088 + lane * 17;
    #pragma unroll
    for (int h = 0; h < 16; h++) rp[h] = acc[h];
  }
  __syncthreads();

  // e-phase: wave w -> h = w and w+8, r = lane
  {
    float s1 = 0.f, s2 = 0.f;
    #pragma unroll
    for (int ww = 0; ww < 8; ww++) {
      s1 += KV[ww * 1088 + lane * 17 + w];
      s2 += KV[ww * 1088 + lane * 17 + w + 8];
    }
    s1 += qbk[b * NHD + w];
    s2 += qbk[b * NHD + w + 8];
    int mk = mask[b * TT + t0 + lane];
    float e1 = mk ? __expf(s1) : 0.f;
    float e2 = mk ? __expf(s2) : 0.f;
    E[lane * 20 + w] = e1;
    E[lane * 20 + w + 8] = e2;
    float sp1 = e1, sp2 = e2;
    #pragma unroll
    for (int m2 = 1; m2 < 64; m2 <<= 1) {
      sp1 += __shfl_xor(sp1, m2);
      sp2 += __shfl_xor(sp2, m2);
    }
    if (lane == 0) {
      Spart[(((size_t)b << 6) + g) * NHD + w] = sp1;
      Spart[(((size_t)b << 6) + g) * NHD + w + 8] = sp2;
    }
  }
  __syncthreads();

  // write PV chunk 0
  #pragma unroll
  for (int m = 0; m < 8; m++) *(float4*)(kvw + (m << 5)) = stg[m];
  __syncthreads();

  // ---------------- PV pass ----------------
  int hq = w & 3;
  for (int c = 0; c < 4; c++) {
    if (c < 3) {
      const float* gs2 = gs + ((c + 1) << 8);
      #pragma unroll
      for (int m = 0; m < 8; m++) stg[m] = *(const float4*)(gs2 + (m << 5));
    }
    if (w < 4) {
      float4 p0 = make_float4(0.f, 0.f, 0.f, 0.f);
      float4 p1 = make_float4(0.f, 0.f, 0.f, 0.f);
      float4 p2 = make_float4(0.f, 0.f, 0.f, 0.f);
      float4 p3 = make_float4(0.f, 0.f, 0.f, 0.f);
      const float* kvp = KV + (lane << 2);
      const float* ep = E + (hq << 2);
      #pragma unroll 8
      for (int r = 0; r < 64; r++) {
        float4 kvq = *(const float4*)(kvp + r * 260);
        float4 ev  = *(const float4*)(ep + r * 20);   // uniform -> broadcast
        p0.x += kvq.x * ev.x; p0.y += kvq.y * ev.x; p0.z += kvq.z * ev.x; p0.w += kvq.w * ev.x;
        p1.x += kvq.x * ev.y; p1.y += kvq.y * ev.y; p1.z += kvq.z * ev.y; p1.w += kvq.w * ev.y;
        p2.x += kvq.x * ev.z; p2.y += kvq.y * ev.z; p2.z += kvq.z * ev.z; p2.w += kvq.w * ev.z;
        p3.x += kvq.x * ev.w; p3.y += kvq.y * ev.w; p3.z += kvq.z * ev.w; p3.w += kvq.w * ev.w;
      }
      float* cp = ctxp + ((((size_t)(b << 6) + g) * NHD + (hq << 2)) << 10) + (c << 8) + (lane << 2);
      *(float4*)(cp)        = p0;
      *(float4*)(cp + 1024) = p1;
      *(float4*)(cp + 2048) = p2;
      *(float4*)(cp + 3072) = p3;
    }
    __syncthreads();
    if (c < 3) {
      #pragma unroll
      for (int m = 0; m < 8; m++) *(float4*)(kvw + (m << 5)) = stg[m];
    }
    __syncthreads();
  }
}

// ---------------- K4: Sinv[b][h] = 1 / sum_g Spart[b][g][h] ----------------
__global__ void k_sinv(const float* __restrict__ Spart, float* __restrict__ Sinv) {
  int tid = threadIdx.x;  // 128
  int b = tid >> 4, h = tid & 15;
  float s = 0.f;
  #pragma unroll 8
  for (int c = 0; c < 64; c++) s += Spart[(size_t)((b << 6) + c) * NHD + h];
  Sinv[tid] = 1.f / s;
}

// ---------------- K4b: ctxin[b][h][i] = sum_g ctxp[b][g][h][i] ----------------
__global__ __launch_bounds__(256) void k_reduce(const float* __restrict__ ctxp,
                                                float* __restrict__ ctxin) {
  int tid = threadIdx.x;
  int b = blockIdx.x >> 4, h = blockIdx.x & 15;
  const float4* cp4 = (const float4*)ctxp;
  float4 s = make_float4(0.f, 0.f, 0.f, 0.f);
  #pragma unroll 8
  for (int g = 0; g < 64; g++) {
    float4 v = cp4[((((size_t)b * 64 + g) * 16 + h) << 8) + tid];
    s.x += v.x; s.y += v.y; s.z += v.z; s.w += v.w;
  }
  ((float4*)ctxin)[(((size_t)(b << 4) + h) << 8) + tid] = s;
}

// ---------------- K6: out[b][h*64+(j%64)] = Sinv[b][h]*(Wv[j,:]·ctxin[b][h][:]) + bv[j] ----------------
__global__ __launch_bounds__(256) void k_out(const float* __restrict__ Wv,
                                             const float* __restrict__ bv,
                                             const float* __restrict__ ctxin,
                                             const float* __restrict__ Sinv,
                                             float* __restrict__ out) {
  __shared__ float cs[BB * HH];  // 32 KB
  int tid = threadIdx.x;
  int h = blockIdx.x >> 4;
  int j0 = blockIdx.x * 4;
  #pragma unroll
  for (int m = 0; m < 8; m++) {
    int idx4 = tid + (m << 8);
    int b = idx4 >> 8, i4 = idx4 & 255;
    ((float4*)cs)[idx4] = ((const float4*)ctxin)[(((b << 4) + h) << 8) + i4];
  }
  __syncthreads();
  int jj = tid >> 6, lane = tid & 63;
  int j = j0 + jj;
  float acc[BB];
  #pragma unroll
  for (int b = 0; b < BB; b++) acc[b] = 0.f;
  #pragma unroll
  for (int k = 0; k < 4; k++) {
    int i = (k << 8) + (lane << 2);
    float4 w = *(const float4*)&Wv[(size_t)j * HH + i];
    #pragma unroll
    for (int b = 0; b < BB; b++) acc[b] += dot4(w, *(const float4*)&cs[b * HH + i]);
  }
  #pragma unroll
  for (int b = 0; b < BB; b++) {
    acc[b] += __shfl_xor(acc[b], 1);  acc[b] += __shfl_xor(acc[b], 2);
    acc[b] += __shfl_xor(acc[b], 4);  acc[b] += __shfl_xor(acc[b], 8);
    acc[b] += __shfl_xor(acc[b], 16); acc[b] += __shfl_xor(acc[b], 32);
  }
  if (lane == 0) {
    float bvj = bv[j];
    #pragma unroll
    for (int b = 0; b < BB; b++)
      out[b * HH + j] = Sinv[b * NHD + h] * acc[b] + bvj;
  }
}

extern "C" void kernel_launch(void* const* d_in, const int* in_sizes, int n_in,
                              void* d_out, int out_size, void* d_ws, size_t ws_size,
                              hipStream_t stream) {
  const float* hid  = (const float*)d_in[0];  // (8, 4097, 1024)
  const float* cell = (const float*)d_in[1];  // (8, 1024)
  const float* Wq   = (const float*)d_in[2];
  const float* bq   = (const float*)d_in[3];
  const float* Wk   = (const float*)d_in[4];
  const float* bk   = (const float*)d_in[5];
  const float* Wv   = (const float*)d_in[6];
  const float* bv   = (const float*)d_in[7];
  const int*  mask  = (const int*)d_in[8];    // (8, 4096)
  float* out = (float*)d_out;                 // (8, 1024)

  float* ws = (float*)d_ws;
  float* qbuf    = ws;             // 8192
  float* qWkT    = ws + 8192;      // 131072   [b][i][16]
  float* qbk     = ws + 139264;    // 128
  float* Spart   = ws + 139392;    // 8192     [b][g(64)][16]
  float* Sinv    = ws + 147584;    // 128
  float* ctxin   = ws + 147712;    // 131072   [b][h][1024]
  float* ctxp    = ws + 278784;    // 8388608  [b][g(64)][h][1024] partials

  hipLaunchKernelGGL(k_q,      dim3(256), dim3(256), 0, stream, cell, Wq, bq, qbuf);
  hipLaunchKernelGGL(k_qwk,    dim3(256), dim3(256), 0, stream, qbuf, Wk, bk, qWkT, qbk);
  hipLaunchKernelGGL(k_sctx,   dim3(512), dim3(512), 0, stream, hid, qWkT, qbk, mask, ctxp, Spart);
  hipLaunchKernelGGL(k_sinv,   dim3(1),   dim3(128), 0, stream, Spart, Sinv);
  hipLaunchKernelGGL(k_reduce, dim3(128), dim3(256), 0, stream, ctxp, ctxin);
  hipLaunchKernelGGL(k_out,    dim3(256), dim3(256), 0, stream, Wv, bv, ctxin, Sinv, out);
}

// Round 4
// 266.032 us; speedup vs baseline: 1.2879x; 1.2879x over previous
//
#include <hip/hip_runtime.h>
#include <math.h>

#define BB 8
#define TT 4096
#define TP1 4097
#define HH 1024
#define NHD 16

__device__ __forceinline__ float dot4(const float4& a, const float4& b) {
  return a.x*b.x + a.y*b.y + a.z*b.z + a.w*b.w;
}

// ---------------- K1: qbuf[b][j] = 0.125*(cell[b,:]·Wq[j,:] + bq[j]) ----------------
__global__ __launch_bounds__(256) void k_q(const float* __restrict__ cell,
                                           const float* __restrict__ Wq,
                                           const float* __restrict__ bq,
                                           float* __restrict__ qbuf) {
  __shared__ float cs[BB * HH];  // 32 KB
  int tid = threadIdx.x;
  #pragma unroll
  for (int m = 0; m < 8; m++) {
    int idx4 = tid + (m << 8);
    ((float4*)cs)[idx4] = ((const float4*)cell)[idx4];
  }
  __syncthreads();
  int jj = tid >> 6, lane = tid & 63;
  int j = blockIdx.x * 4 + jj;
  float acc[BB];
  #pragma unroll
  for (int b = 0; b < BB; b++) acc[b] = 0.f;
  #pragma unroll
  for (int k = 0; k < 4; k++) {
    int i = (k << 8) + (lane << 2);
    float4 w = *(const float4*)&Wq[(size_t)j * HH + i];
    #pragma unroll
    for (int b = 0; b < BB; b++) acc[b] += dot4(w, *(const float4*)&cs[b * HH + i]);
  }
  #pragma unroll
  for (int b = 0; b < BB; b++) {
    acc[b] += __shfl_xor(acc[b], 1);  acc[b] += __shfl_xor(acc[b], 2);
    acc[b] += __shfl_xor(acc[b], 4);  acc[b] += __shfl_xor(acc[b], 8);
    acc[b] += __shfl_xor(acc[b], 16); acc[b] += __shfl_xor(acc[b], 32);
  }
  if (lane == 0) {
    float bqv = bq[j];
    #pragma unroll
    for (int b = 0; b < BB; b++) qbuf[b * HH + j] = 0.125f * (acc[b] + bqv);
  }
}

// ---------------- K2: qWkT[b][i][h] = sum_d qbuf[b][h*64+d]*Wk[h*64+d][i]; qbk[b][h] ----------------
__global__ __launch_bounds__(256) void k_qwk(const float* __restrict__ qbuf,
                                             const float* __restrict__ Wk,
                                             const float* __restrict__ bk,
                                             float* __restrict__ qWkT,
                                             float* __restrict__ qbk) {
  __shared__ float q_s[BB * 64];
  __shared__ float red[4 * 64 * 9];  // padded +1
  int tid = threadIdx.x;
  int h = blockIdx.x >> 4, ic = blockIdx.x & 15;
  if (tid < 128) {
    int b = tid >> 4, dq = tid & 15;
    ((float4*)q_s)[tid] = ((const float4*)qbuf)[(b << 8) + (h << 4) + dq];
  }
  __syncthreads();
  int dg = tid >> 6, lane = tid & 63;
  int i = (ic << 6) + lane;
  float acc[BB];
  #pragma unroll
  for (int b = 0; b < BB; b++) acc[b] = 0.f;
  #pragma unroll
  for (int dd = 0; dd < 16; dd++) {
    int d = (dg << 4) + dd;
    float wk = Wk[(size_t)((h << 6) + d) * HH + i];
    #pragma unroll
    for (int b = 0; b < BB; b++) acc[b] += q_s[(b << 6) + d] * wk;
  }
  #pragma unroll
  for (int b = 0; b < BB; b++) red[((dg << 6) + lane) * 9 + b] = acc[b];
  __syncthreads();
  #pragma unroll
  for (int r = 0; r < 2; r++) {
    int o = tid + (r << 8);           // 512 outputs = 64 i x 8 b
    int il = o >> 3, b = o & 7;
    float s = 0.f;
    #pragma unroll
    for (int g = 0; g < 4; g++) s += red[((g << 6) + il) * 9 + b];
    qWkT[((size_t)(b << 10) + (ic << 6) + il) * NHD + h] = s;
  }
  if (ic == 0 && tid < 8) {
    float s = 0.f;
    for (int d = 0; d < 64; d++) s += q_s[(tid << 6) + d] * bk[(h << 6) + d];
    qbk[tid * NHD + h] = s;
  }
}

// ---------------- K3 (FUSED v4): async global_load_lds staging, zero staging VGPRs ----------------
// grid 512 = b(8) x g(64); block 512 thr (8 waves); 64 rows/block.
// 8 half-chunks of 128 i; KV double-buffered [2][64][128] = 64 KB linear LDS,
// staged via global_load_lds width=16 (wave-uniform dest + lane*16; source quad
// index XOR-swizzled by row&7; reads apply the same XOR -> conflict-free/2-way).
// One barrier per half-chunk: publishes the async loads AND protects the swap;
// loads for c+1 issued BEFORE computing c.
// Scores: lane = row; wave w owns 16 i per half-chunk; q via wave-uniform float4
// loads (scalarize to s_load_dwordx4; qWkT L2-resident). acc[16]/lane.
// Red overlay [8][64][17] in KV region; e-phase; E[64][20].
// PV: re-stage same half-chunks (hid L3-resident); waves 0-3: hq=w, lane: sub=rowhalf,
// iq=lane&31; per row 1 kv b128 (contiguous permuted row -> conflict-free) +
// 1 uniform e b128 (broadcast) + 16 FMAs; halves combined via shfl_xor(32).
__global__ __launch_bounds__(512) void k_sctx(const float* __restrict__ hid,
                                              const float* __restrict__ qWkT,
                                              const float* __restrict__ qbk,
                                              const int* __restrict__ mask,
                                              float* __restrict__ ctxp,
                                              float* __restrict__ Spart) {
  __shared__ float S[16384];   // [2][64][128]; red overlay [8][64][17] = 8704 floats
  __shared__ float E[1280];    // [64][20]
  int tid = threadIdx.x;
  int b = blockIdx.x >> 6, g = blockIdx.x & 63;
  int t0 = g << 6;
  int w = __builtin_amdgcn_readfirstlane(tid >> 6);
  int lane = tid & 63;
  const float* src = hid + ((size_t)b * TP1 + t0) * HH;
  int sub = lane >> 5, q31 = lane & 31;

  // async stage of half-chunk cc into buffer buf (wave w stages rows w*8..w*8+7)
  #define STAGE(cc, buf)                                                            \
    {                                                                               \
      _Pragma("unroll")                                                             \
      for (int j = 0; j < 4; j++) {                                                 \
        int row0 = (w << 3) + (j << 1);                                             \
        int row = row0 + sub;                                                       \
        const float* gp = src + (size_t)row * HH + ((cc) << 7) +                    \
                          ((q31 ^ (row & 7)) << 2);                                 \
        float* dp = &S[((buf) << 13) + row0 * 128];                                 \
        __builtin_amdgcn_global_load_lds(                                           \
            (const __attribute__((address_space(1))) unsigned int*)gp,              \
            (__attribute__((address_space(3))) unsigned int*)dp, 16, 0, 0);         \
      }                                                                             \
    }

  // ---------------- scores pass ----------------
  STAGE(0, 0);
  __syncthreads();

  float acc[16];
  #pragma unroll
  for (int h = 0; h < 16; h++) acc[h] = 0.f;
  const float* qb = qWkT + ((size_t)b << 14);

  for (int c = 0; c < 8; c++) {
    if (c < 7) STAGE(c + 1, (c + 1) & 1);
    const float* sb = &S[(c & 1) << 13];
    #pragma unroll
    for (int s = 0; s < 4; s++) {
      int q = (w << 2) + s;
      float4 kvq = *(const float4*)&sb[lane * 128 + ((q ^ (lane & 7)) << 2)];
      const float* qp = qb + (((size_t)(c << 7) + (q << 2)) << 4);
      #pragma unroll
      for (int ii = 0; ii < 4; ii++) {
        float kvv = (ii == 0) ? kvq.x : (ii == 1) ? kvq.y : (ii == 2) ? kvq.z : kvq.w;
        const float* qi = qp + (ii << 4);
        float4 q0 = *(const float4*)(qi);
        float4 q1 = *(const float4*)(qi + 4);
        float4 q2 = *(const float4*)(qi + 8);
        float4 q3 = *(const float4*)(qi + 12);
        acc[0]  += kvv * q0.x;  acc[1]  += kvv * q0.y;
        acc[2]  += kvv * q0.z;  acc[3]  += kvv * q0.w;
        acc[4]  += kvv * q1.x;  acc[5]  += kvv * q1.y;
        acc[6]  += kvv * q1.z;  acc[7]  += kvv * q1.w;
        acc[8]  += kvv * q2.x;  acc[9]  += kvv * q2.y;
        acc[10] += kvv * q2.z;  acc[11] += kvv * q2.w;
        acc[12] += kvv * q3.x;  acc[13] += kvv * q3.y;
        acc[14] += kvv * q3.z;  acc[15] += kvv * q3.w;
      }
    }
    __syncthreads();
  }

  // red overlay: red[w][r][h] at S[w*1088 + r*17 + h] (17-stride: conflict-free)
  {
    float* rp = S + w * 1088 + lane * 17;
    #pragma unroll
    for (int h = 0; h < 16; h++) rp[h] = acc[h];
  }
  __syncthreads();

  // e-phase: wave w -> h = w and w+8, r = lane
  {
    float s1 = 0.f, s2 = 0.f;
    #pragma unroll
    for (int ww = 0; ww < 8; ww++) {
      s1 += S[ww * 1088 + lane * 17 + w];
      s2 += S[ww * 1088 + lane * 17 + w + 8];
    }
    s1 += qbk[b * NHD + w];
    s2 += qbk[b * NHD + w + 8];
    int mk = mask[b * TT + t0 + lane];
    float e1 = mk ? __expf(s1) : 0.f;
    float e2 = mk ? __expf(s2) : 0.f;
    E[lane * 20 + w] = e1;
    E[lane * 20 + w + 8] = e2;
    float sp1 = e1, sp2 = e2;
    #pragma unroll
    for (int m2 = 1; m2 < 64; m2 <<= 1) {
      sp1 += __shfl_xor(sp1, m2);
      sp2 += __shfl_xor(sp2, m2);
    }
    if (lane == 0) {
      Spart[(((size_t)b << 6) + g) * NHD + w] = sp1;
      Spart[(((size_t)b << 6) + g) * NHD + w + 8] = sp2;
    }
  }
  __syncthreads();

  // ---------------- PV pass ----------------
  STAGE(0, 0);
  __syncthreads();

  for (int c = 0; c < 8; c++) {
    if (c < 7) STAGE(c + 1, (c + 1) & 1);
    if (w < 4) {
      float4 p0 = make_float4(0.f, 0.f, 0.f, 0.f);
      float4 p1 = make_float4(0.f, 0.f, 0.f, 0.f);
      float4 p2 = make_float4(0.f, 0.f, 0.f, 0.f);
      float4 p3 = make_float4(0.f, 0.f, 0.f, 0.f);
      const float* sb = &S[(c & 1) << 13];
      #pragma unroll 8
      for (int r = 0; r < 32; r++) {
        int row = (sub << 5) + r;
        float4 kvq = *(const float4*)&sb[row * 128 + ((q31 ^ (row & 7)) << 2)];
        float4 ev  = *(const float4*)&E[row * 20 + (w << 2)];   // uniform -> broadcast
        p0.x += kvq.x * ev.x; p0.y += kvq.y * ev.x; p0.z += kvq.z * ev.x; p0.w += kvq.w * ev.x;
        p1.x += kvq.x * ev.y; p1.y += kvq.y * ev.y; p1.z += kvq.z * ev.y; p1.w += kvq.w * ev.y;
        p2.x += kvq.x * ev.z; p2.y += kvq.y * ev.z; p2.z += kvq.z * ev.z; p2.w += kvq.w * ev.z;
        p3.x += kvq.x * ev.w; p3.y += kvq.y * ev.w; p3.z += kvq.z * ev.w; p3.w += kvq.w * ev.w;
      }
      // combine row-halves: lanes l and l+32 hold the same (iq, h)
      p0.x += __shfl_xor(p0.x, 32); p0.y += __shfl_xor(p0.y, 32);
      p0.z += __shfl_xor(p0.z, 32); p0.w += __shfl_xor(p0.w, 32);
      p1.x += __shfl_xor(p1.x, 32); p1.y += __shfl_xor(p1.y, 32);
      p1.z += __shfl_xor(p1.z, 32); p1.w += __shfl_xor(p1.w, 32);
      p2.x += __shfl_xor(p2.x, 32); p2.y += __shfl_xor(p2.y, 32);
      p2.z += __shfl_xor(p2.z, 32); p2.w += __shfl_xor(p2.w, 32);
      p3.x += __shfl_xor(p3.x, 32); p3.y += __shfl_xor(p3.y, 32);
      p3.z += __shfl_xor(p3.z, 32); p3.w += __shfl_xor(p3.w, 32);
      if (sub == 0) {
        float* cp = ctxp + ((((size_t)(b << 6) + g) * NHD + (w << 2)) << 10) +
                    (c << 7) + (q31 << 2);
        *(float4*)(cp)        = p0;
        *(float4*)(cp + 1024) = p1;
        *(float4*)(cp + 2048) = p2;
        *(float4*)(cp + 3072) = p3;
      }
    }
    __syncthreads();
  }
  #undef STAGE
}

// ---------------- K4: Sinv[b][h] = 1 / sum_g Spart[b][g][h] ----------------
__global__ void k_sinv(const float* __restrict__ Spart, float* __restrict__ Sinv) {
  int tid = threadIdx.x;  // 128
  int b = tid >> 4, h = tid & 15;
  float s = 0.f;
  #pragma unroll 8
  for (int c = 0; c < 64; c++) s += Spart[(size_t)((b << 6) + c) * NHD + h];
  Sinv[tid] = 1.f / s;
}

// ---------------- K4b: ctxin[b][h][i] = sum_g ctxp[b][g][h][i] ----------------
__global__ __launch_bounds__(256) void k_reduce(const float* __restrict__ ctxp,
                                                float* __restrict__ ctxin) {
  int tid = threadIdx.x;
  int b = blockIdx.x >> 4, h = blockIdx.x & 15;
  const float4* cp4 = (const float4*)ctxp;
  float4 s = make_float4(0.f, 0.f, 0.f, 0.f);
  #pragma unroll 8
  for (int g = 0; g < 64; g++) {
    float4 v = cp4[((((size_t)b * 64 + g) * 16 + h) << 8) + tid];
    s.x += v.x; s.y += v.y; s.z += v.z; s.w += v.w;
  }
  ((float4*)ctxin)[(((size_t)(b << 4) + h) << 8) + tid] = s;
}

// ---------------- K6: out[b][h*64+(j%64)] = Sinv[b][h]*(Wv[j,:]·ctxin[b][h][:]) + bv[j] ----------------
__global__ __launch_bounds__(256) void k_out(const float* __restrict__ Wv,
                                             const float* __restrict__ bv,
                                             const float* __restrict__ ctxin,
                                             const float* __restrict__ Sinv,
                                             float* __restrict__ out) {
  __shared__ float cs[BB * HH];  // 32 KB
  int tid = threadIdx.x;
  int h = blockIdx.x >> 4;
  int j0 = blockIdx.x * 4;
  #pragma unroll
  for (int m = 0; m < 8; m++) {
    int idx4 = tid + (m << 8);
    int b = idx4 >> 8, i4 = idx4 & 255;
    ((float4*)cs)[idx4] = ((const float4*)ctxin)[(((b << 4) + h) << 8) + i4];
  }
  __syncthreads();
  int jj = tid >> 6, lane = tid & 63;
  int j = j0 + jj;
  float acc[BB];
  #pragma unroll
  for (int b = 0; b < BB; b++) acc[b] = 0.f;
  #pragma unroll
  for (int k = 0; k < 4; k++) {
    int i = (k << 8) + (lane << 2);
    float4 w = *(const float4*)&Wv[(size_t)j * HH + i];
    #pragma unroll
    for (int b = 0; b < BB; b++) acc[b] += dot4(w, *(const float4*)&cs[b * HH + i]);
  }
  #pragma unroll
  for (int b = 0; b < BB; b++) {
    acc[b] += __shfl_xor(acc[b], 1);  acc[b] += __shfl_xor(acc[b], 2);
    acc[b] += __shfl_xor(acc[b], 4);  acc[b] += __shfl_xor(acc[b], 8);
    acc[b] += __shfl_xor(acc[b], 16); acc[b] += __shfl_xor(acc[b], 32);
  }
  if (lane == 0) {
    float bvj = bv[j];
    #pragma unroll
    for (int b = 0; b < BB; b++)
      out[b * HH + j] = Sinv[b * NHD + h] * acc[b] + bvj;
  }
}

extern "C" void kernel_launch(void* const* d_in, const int* in_sizes, int n_in,
                              void* d_out, int out_size, void* d_ws, size_t ws_size,
                              hipStream_t stream) {
  const float* hid  = (const float*)d_in[0];  // (8, 4097, 1024)
  const float* cell = (const float*)d_in[1];  // (8, 1024)
  const float* Wq   = (const float*)d_in[2];
  const float* bq   = (const float*)d_in[3];
  const float* Wk   = (const float*)d_in[4];
  const float* bk   = (const float*)d_in[5];
  const float* Wv   = (const float*)d_in[6];
  const float* bv   = (const float*)d_in[7];
  const int*  mask  = (const int*)d_in[8];    // (8, 4096)
  float* out = (float*)d_out;                 // (8, 1024)

  float* ws = (float*)d_ws;
  float* qbuf    = ws;             // 8192
  float* qWkT    = ws + 8192;      // 131072   [b][i][16]
  float* qbk     = ws + 139264;    // 128
  float* Spart   = ws + 139392;    // 8192     [b][g(64)][16]
  float* Sinv    = ws + 147584;    // 128
  float* ctxin   = ws + 147712;    // 131072   [b][h][1024]
  float* ctxp    = ws + 278784;    // 8388608  [b][g(64)][h][1024] partials

  hipLaunchKernelGGL(k_q,      dim3(256), dim3(256), 0, stream, cell, Wq, bq, qbuf);
  hipLaunchKernelGGL(k_qwk,    dim3(256), dim3(256), 0, stream, qbuf, Wk, bk, qWkT, qbk);
  hipLaunchKernelGGL(k_sctx,   dim3(512), dim3(512), 0, stream, hid, qWkT, qbk, mask, ctxp, Spart);
  hipLaunchKernelGGL(k_sinv,   dim3(1),   dim3(128), 0, stream, Spart, Sinv);
  hipLaunchKernelGGL(k_reduce, dim3(128), dim3(256), 0, stream, ctxp, ctxin);
  hipLaunchKernelGGL(k_out,    dim3(256), dim3(256), 0, stream, Wv, bv, ctxin, Sinv, out);
}